// Round 3
// baseline (77037.646 us; speedup 1.0000x reference)
//
#include <hip/hip_runtime.h>
#include <hip/hip_cooperative_groups.h>
#include <math.h>

namespace cg = cooperative_groups;

// =====================================================================
// AttendAndSpell: 128-step attention LSTM decoder with exact JAX threefry
// sampling replication. All compute fp32 (no fp32 MFMA on CDNA4; bf16
// would flip gumbel-argmax decisions).
//
// R3: persistent cooperative kernel, phase bodies verbatim from the
//     passing baseline. NEW vs R2: explicit __threadfence() (agent-scope
//     release/acquire -> L2 writeback/invalidate across XCDs) around every
//     grid.sync(), since R1/R2 produced identical deterministic drift
//     consistent with cross-XCD L2 staleness (per-XCD L2s are write-back
//     and non-coherent; kernel boundaries flush them, grid.sync may not).
//     Also: no __restrict__ on inlined phase helpers; host falls back to
//     the verbatim 6-kernel baseline loop if coop launch is rejected.
// =====================================================================

#define JAX_PARTITIONABLE 1

#define B_   128
#define HID_ 512
#define VOC_ 64
#define T_   128

// workspace offsets in floats
#define S0_OFF    0u
#define CS0_OFF   65536u
#define S1_OFF    131072u
#define CS1_OFF   196608u
#define SQT_OFF   262144u
#define CPR_OFF   327680u
#define AMAT_OFF  393216u     // 512x512
#define W1PSI_OFF 655360u     // 2048x512
#define BIAS0_OFF 1703936u    // 2048
#define V_OFF     1705984u    // 512
#define PART_OFF  1706496u    // 16*128*2048
#define GUM_OFF   5900800u    // 128*128*64
#define UB_OFF    6949376u    // 128*128
#define Z_OFF     6965760u    // 128 ints

#define TF_TINY 1.17549435e-38f

// ----------------------- threefry2x32 ---------------------------------
__device__ __forceinline__ void tf2x32(unsigned k0, unsigned k1,
                                       unsigned& x0, unsigned& x1) {
  unsigned ks2 = k0 ^ k1 ^ 0x1BD11BDAu;
  const unsigned ks[3] = {k0, k1, ks2};
  const int rot0[4] = {13, 15, 26, 6};
  const int rot1[4] = {17, 29, 16, 24};
  x0 += ks[0]; x1 += ks[1];
  #pragma unroll
  for (int i = 0; i < 5; ++i) {
    #pragma unroll
    for (int r = 0; r < 4; ++r) {
      int rr = (i & 1) ? rot1[r] : rot0[r];
      x0 += x1;
      x1 = (x1 << rr) | (x1 >> (32 - rr));
      x1 ^= x0;
    }
    x0 += ks[(i + 1) % 3];
    x1 += ks[(i + 2) % 3] + (unsigned)(i + 1);
  }
}

__device__ __forceinline__ float bits_to_unit(unsigned bits) {
  return __uint_as_float((bits >> 9) | 0x3f800000u) - 1.0f;
}

__global__ __launch_bounds__(256) void k_random(const int* __restrict__ y,
                                                float* __restrict__ gum,
                                                float* __restrict__ ub,
                                                int* __restrict__ z) {
  int t = blockIdx.x, tid = threadIdx.x;
  unsigned ka, kb, k1a, k1b, k2a, k2b;
#if JAX_PARTITIONABLE
  ka = 0u; kb = (unsigned)t;
  tf2x32(0u, 42u, ka, kb);
  k1a = 0u; k1b = 0u; tf2x32(ka, kb, k1a, k1b);
  k2a = 0u; k2b = 1u; tf2x32(ka, kb, k2a, k2b);
  for (int j = tid; j < B_ * VOC_; j += 256) {
    unsigned x0 = 0u, x1 = (unsigned)j;
    tf2x32(k1a, k1b, x0, x1);
    unsigned bits = x0 ^ x1;
    float f = bits_to_unit(bits);
    float u = fmaxf(TF_TINY, f * (1.0f - TF_TINY) + TF_TINY);
    gum[(size_t)t * (B_ * VOC_) + j] = -logf(-logf(u));
  }
  if (tid < B_) {
    unsigned x0 = 0u, x1 = (unsigned)tid;
    tf2x32(k2a, k2b, x0, x1);
    ub[t * B_ + tid] = bits_to_unit(x0 ^ x1);
  }
#else
  {
    unsigned x0, x1, y0, y1;
    if (t < 64) {
      x0 = 2u * t;     x1 = 128u + 2u * t;     tf2x32(0u, 42u, x0, x1); ka = x0;
      y0 = 2u * t + 1; y1 = 128u + 2u * t + 1; tf2x32(0u, 42u, y0, y1); kb = y0;
    } else {
      x0 = 2u * t - 128u; x1 = 2u * t;         tf2x32(0u, 42u, x0, x1); ka = x1;
      y0 = 2u * t - 127u; y1 = 2u * t + 1;     tf2x32(0u, 42u, y0, y1); kb = y1;
    }
    unsigned e0a = 0u, e0b = 2u; tf2x32(ka, kb, e0a, e0b);
    unsigned e1a = 1u, e1b = 3u; tf2x32(ka, kb, e1a, e1b);
    k1a = e0a; k1b = e1a; k2a = e0b; k2b = e1b;
  }
  for (int j = tid; j < B_ * VOC_; j += 256) {
    unsigned x0, x1, bits;
    if (j < 4096) { x0 = (unsigned)j; x1 = (unsigned)(4096 + j); tf2x32(k1a, k1b, x0, x1); bits = x0; }
    else          { x0 = (unsigned)(j - 4096); x1 = (unsigned)j; tf2x32(k1a, k1b, x0, x1); bits = x1; }
    float f = bits_to_unit(bits);
    float u = fmaxf(TF_TINY, f * (1.0f - TF_TINY) + TF_TINY);
    gum[(size_t)t * (B_ * VOC_) + j] = -logf(-logf(u));
  }
  if (tid < B_) {
    unsigned x0, x1, bits;
    if (tid < 64) { x0 = (unsigned)tid; x1 = (unsigned)(64 + tid); tf2x32(k2a, k2b, x0, x1); bits = x0; }
    else          { x0 = (unsigned)(tid - 64); x1 = (unsigned)tid; tf2x32(k2a, k2b, x0, x1); bits = x1; }
    ub[t * B_ + tid] = bits_to_unit(bits);
  }
#endif
  if (t == 0 && tid < B_) z[tid] = y[tid * (T_ + 1)];
}

// ----------------------- precompute folds ------------------------------
__global__ __launch_bounds__(256) void k_fold_misc(
    const float* __restrict__ psi_w, const float* __restrict__ phi_b,
    const float* __restrict__ w_ih0, const float* __restrict__ psi_b,
    const float* __restrict__ b_ih0, const float* __restrict__ b_hh0,
    float* __restrict__ vvec, float* __restrict__ bias0) {
  int gid = blockIdx.x * 256 + threadIdx.x;
  if (gid < 512) {
    float acc = 0.f;
    for (int j = 0; j < 512; ++j) acc += psi_w[j * 512 + gid] * phi_b[j];
    vvec[gid] = acc;
  } else if (gid < 512 + 2048) {
    int j = gid - 512;
    float acc = b_ih0[j] + b_hh0[j];
    const float* wr = w_ih0 + (size_t)j * 576 + 64;
    for (int d = 0; d < 512; ++d) acc += wr[d] * psi_b[d];
    bias0[j] = acc;
  }
}

__global__ __launch_bounds__(256) void k_gemm_tn(
    const float* __restrict__ A, const float* __restrict__ B, float* __restrict__ C,
    int K, int lda, int ldb, int ldc) {
  __shared__ float As[32][33], Bs[32][33];
  int n0 = blockIdx.x * 32, m0 = blockIdx.y * 32;
  int t = threadIdx.x, tx = t & 31, ty = t >> 5;
  float acc[4] = {0.f, 0.f, 0.f, 0.f};
  for (int k0 = 0; k0 < K; k0 += 32) {
    for (int l = t; l < 1024; l += 256) {
      int jj = l >> 5, mm = l & 31;
      As[jj][mm] = A[(size_t)(k0 + jj) * lda + m0 + mm];
      Bs[jj][mm] = B[(size_t)(k0 + jj) * ldb + n0 + mm];
    }
    __syncthreads();
    #pragma unroll 8
    for (int jj = 0; jj < 32; ++jj) {
      float bv = Bs[jj][tx];
      #pragma unroll
      for (int q = 0; q < 4; ++q) acc[q] += As[jj][ty + 8 * q] * bv;
    }
    __syncthreads();
  }
  #pragma unroll
  for (int q = 0; q < 4; ++q) C[(size_t)(m0 + ty + 8 * q) * ldc + n0 + tx] = acc[q];
}

__global__ __launch_bounds__(256) void k_gemm_nn(
    const float* __restrict__ A, const float* __restrict__ B, float* __restrict__ C,
    int K, int lda, int aoff, int ldb, int ldc) {
  __shared__ float As[32][33], Bs[32][33];
  int n0 = blockIdx.x * 32, m0 = blockIdx.y * 32;
  int t = threadIdx.x, tx = t & 31, ty = t >> 5;
  float acc[4] = {0.f, 0.f, 0.f, 0.f};
  for (int k0 = 0; k0 < K; k0 += 32) {
    for (int l = t; l < 1024; l += 256) {
      int r = l >> 5, c = l & 31;
      As[c][r] = A[(size_t)(m0 + r) * lda + aoff + k0 + c];
      Bs[r][c] = B[(size_t)(k0 + r) * ldb + n0 + c];
    }
    __syncthreads();
    #pragma unroll 8
    for (int kk = 0; kk < 32; ++kk) {
      float bv = Bs[kk][tx];
      #pragma unroll
      for (int q = 0; q < 4; ++q) acc[q] += As[kk][ty + 8 * q] * bv;
    }
    __syncthreads();
  }
  #pragma unroll
  for (int q = 0; q < 4; ++q) C[(size_t)(m0 + ty + 8 * q) * ldc + n0 + tx] = acc[q];
}

__global__ __launch_bounds__(256) void k_sqt_init(const float* __restrict__ vvec,
                                                  float* __restrict__ sqt) {
  int lin = blockIdx.x * 256 + threadIdx.x;
  if (lin < B_ * HID_) sqt[lin] = vvec[lin & 511];
}

// =====================================================================
// Baseline per-step kernels (verbatim, known-passing) — used as the
// fallback path if cooperative launch is unavailable.
// =====================================================================

__global__ __launch_bounds__(256) void k_attn(const float* __restrict__ h,
                                              const float* __restrict__ sqt,
                                              float* __restrict__ cpr) {
  __shared__ float hs[16 * 512];
  __shared__ float es[16];
  __shared__ float ps[16];
  int b = blockIdx.x, t = threadIdx.x;
  const float* hb = h + (size_t)b * 512 * 512;
  const float* sq = sqt + b * 512;
  int krow = t >> 4, g = t & 15;
  float m = -INFINITY, l = 0.f, a0 = 0.f, a1 = 0.f;
  int d0 = t, d1 = t + 256;
  for (int r0 = 0; r0 < 512; r0 += 16) {
    __syncthreads();
    const float* hr = hb + (size_t)(r0 + krow) * 512;
    float ep = 0.f;
    #pragma unroll
    for (int i = 0; i < 8; ++i) {
      int d = i * 64 + g * 4;
      float4 hv = *(const float4*)(hr + d);
      float4 sv = *(const float4*)(sq + d);
      ep += hv.x * sv.x + hv.y * sv.y + hv.z * sv.z + hv.w * sv.w;
      *(float4*)(&hs[krow * 512 + d]) = hv;
    }
    ep += __shfl_xor(ep, 1);
    ep += __shfl_xor(ep, 2);
    ep += __shfl_xor(ep, 4);
    ep += __shfl_xor(ep, 8);
    if (g == 0) es[krow] = ep;
    __syncthreads();
    float mc = es[0];
    #pragma unroll
    for (int k = 1; k < 16; ++k) mc = fmaxf(mc, es[k]);
    float mn = fmaxf(m, mc);
    if (t < 16) ps[t] = expf(es[t] - mn);
    __syncthreads();
    float sc = expf(m - mn);
    float ls = 0.f;
    float n0 = a0 * sc, n1 = a1 * sc;
    #pragma unroll
    for (int k = 0; k < 16; ++k) {
      float p = ps[k];
      ls += p;
      n0 += p * hs[k * 512 + d0];
      n1 += p * hs[k * 512 + d1];
    }
    m = mn; l = l * sc + ls; a0 = n0; a1 = n1;
  }
  cpr[b * 512 + d0] = a0 / l;
  cpr[b * 512 + d1] = a1 / l;
}

__global__ __launch_bounds__(256) void k_lstm_gemm(
    const float* __restrict__ X0, const float* __restrict__ W0,
    const float* __restrict__ X1, const float* __restrict__ W1,
    float* __restrict__ part) {
  __shared__ float Xs[16][128];
  __shared__ float Ws[16][128];
  int t = threadIdx.x;
  int jt = blockIdx.x * 128;
  int s = blockIdx.y;
  const float* X; const float* W; int kbase;
  if (s < 8) { X = X0; W = W0; kbase = s * 64; }
  else       { X = X1; W = W1; kbase = (s - 8) * 64; }
  float acc[8][8];
  #pragma unroll
  for (int i = 0; i < 8; ++i)
    #pragma unroll
    for (int q = 0; q < 8; ++q) acc[i][q] = 0.f;
  int b0 = (t & 15) * 8, j0 = (t >> 4) * 8;
  for (int kk = 0; kk < 64; kk += 16) {
    #pragma unroll
    for (int lo = 0; lo < 2; ++lo) {
      int idx = t + lo * 256;
      int row = idx >> 2;
      int kq = (idx & 3) * 4;
      float4 xv = *(const float4*)(X + (size_t)row * 512 + kbase + kk + kq);
      float4 wv = *(const float4*)(W + (size_t)(jt + row) * 512 + kbase + kk + kq);
      Xs[kq + 0][row] = xv.x; Xs[kq + 1][row] = xv.y;
      Xs[kq + 2][row] = xv.z; Xs[kq + 3][row] = xv.w;
      Ws[kq + 0][row] = wv.x; Ws[kq + 1][row] = wv.y;
      Ws[kq + 2][row] = wv.z; Ws[kq + 3][row] = wv.w;
    }
    __syncthreads();
    #pragma unroll
    for (int k = 0; k < 16; ++k) {
      float4 xa = *(const float4*)&Xs[k][b0];
      float4 xb = *(const float4*)&Xs[k][b0 + 4];
      float4 wa = *(const float4*)&Ws[k][j0];
      float4 wb = *(const float4*)&Ws[k][j0 + 4];
      float xr[8] = {xa.x, xa.y, xa.z, xa.w, xb.x, xb.y, xb.z, xb.w};
      float wr[8] = {wa.x, wa.y, wa.z, wa.w, wb.x, wb.y, wb.z, wb.w};
      #pragma unroll
      for (int i = 0; i < 8; ++i)
        #pragma unroll
        for (int q = 0; q < 8; ++q) acc[i][q] += xr[i] * wr[q];
    }
    __syncthreads();
  }
  #pragma unroll
  for (int i = 0; i < 8; ++i) {
    float* pr = part + ((size_t)(s * 128 + b0 + i)) * 2048 + jt + j0;
    *(float4*)pr = make_float4(acc[i][0], acc[i][1], acc[i][2], acc[i][3]);
    *(float4*)(pr + 4) = make_float4(acc[i][4], acc[i][5], acc[i][6], acc[i][7]);
  }
}

__device__ __forceinline__ float sigm(float x) { return 1.0f / (1.0f + expf(-x)); }

__global__ __launch_bounds__(256) void k_lstm_cell(
    const float* __restrict__ part, const float* __restrict__ biasA,
    const float* __restrict__ bi, const float* __restrict__ bh,
    const float* __restrict__ woh, int ldoh,
    const int* __restrict__ z, float* __restrict__ s, float* __restrict__ cs) {
  int lin = blockIdx.x * 256 + threadIdx.x;
  int b = lin >> 9, d = lin & 511;
  int zb = woh ? z[b] : 0;
  float g4[4];
  #pragma unroll
  for (int g = 0; g < 4; ++g) {
    int j = g * 512 + d;
    float sum = biasA ? biasA[j] : (bi[j] + bh[j]);
    if (woh) sum += woh[(size_t)j * ldoh + zb];
    #pragma unroll
    for (int sl = 0; sl < 16; ++sl)
      sum += part[((size_t)(sl * 128 + b)) * 2048 + j];
    g4[g] = sum;
  }
  float ig = sigm(g4[0]), fg = sigm(g4[1]);
  float gg = tanhf(g4[2]), og = sigm(g4[3]);
  float cn = fg * cs[lin] + ig * gg;
  float sn = og * tanhf(cn);
  cs[lin] = cn;
  s[lin] = sn;
}

__global__ __launch_bounds__(256) void k_out_sample_sqt(
    int t, const float* __restrict__ s1, const float* __restrict__ outw,
    const float* __restrict__ outb, const float* __restrict__ Amat,
    const float* __restrict__ vvec, const float* __restrict__ gum,
    const float* __restrict__ ub, const int* __restrict__ y,
    float* __restrict__ out, float* __restrict__ sqt, int* __restrict__ z) {
  __shared__ float sl[512];
  __shared__ float red[256];
  int tid = threadIdx.x;
  if (blockIdx.x < 128) {
    int b = blockIdx.x;
    for (int i = tid; i < 512; i += 256) sl[i] = s1[b * 512 + i];
    __syncthreads();
    int v = tid & 63, kg = tid >> 6;
    const float* wr = outw + (size_t)v * 512 + kg * 128;
    const float* sr = sl + kg * 128;
    float sum = 0.f;
    #pragma unroll 8
    for (int k = 0; k < 128; k += 4) {
      float4 w4 = *(const float4*)(wr + k);
      float4 s4 = *(const float4*)(sr + k);
      sum += w4.x * s4.x + w4.y * s4.y + w4.z * s4.z + w4.w * s4.w;
    }
    red[kg * 64 + v] = sum;
    __syncthreads();
    if (tid < 64) {
      float o = red[tid] + red[64 + tid] + red[128 + tid] + red[192 + tid] + outb[tid];
      out[((size_t)b * T_ + t) * VOC_ + tid] = o;
      float val = o + gum[((size_t)t * B_ + b) * VOC_ + tid];
      int idx = tid;
      #pragma unroll
      for (int off = 1; off < 64; off <<= 1) {
        float ov = __shfl_xor(val, off);
        int oi = __shfl_xor(idx, off);
        if (ov > val || (ov == val && oi < idx)) { val = ov; idx = oi; }
      }
      if (tid == 0) {
        float u = ub[t * B_ + b];
        z[b] = (u < 0.1f) ? idx : y[b * (T_ + 1) + t + 1];
      }
    }
  } else {
    int b = blockIdx.x - 128;
    for (int i = tid; i < 512; i += 256) sl[i] = s1[b * 512 + i];
    __syncthreads();
    int d0 = tid, d1 = tid + 256;
    float a0 = vvec[d0], a1 = vvec[d1];
    const float* r0 = Amat + (size_t)d0 * 512;
    const float* r1 = Amat + (size_t)d1 * 512;
    for (int k = 0; k < 512; k += 4) {
      float4 s4 = *(const float4*)(sl + k);
      float4 a4 = *(const float4*)(r0 + k);
      float4 b4 = *(const float4*)(r1 + k);
      a0 += a4.x * s4.x + a4.y * s4.y + a4.z * s4.z + a4.w * s4.w;
      a1 += b4.x * s4.x + b4.y * s4.y + b4.z * s4.z + b4.w * s4.w;
    }
    sqt[b * 512 + d0] = a0;
    sqt[b * 512 + d1] = a1;
  }
}

// =====================================================================
// Persistent-loop phase helpers — same bodies, NO __restrict__ (avoid
// scoped-noalias after inlining), shared-mem passed as plain pointers.
// =====================================================================

__device__ __forceinline__ void attn_block(
    const float* h, const float* sqt, float* cpr,
    float* hs, float* es, float* ps, int b, int tid) {
  const float* hb = h + (size_t)b * 512 * 512;
  const float* sq = sqt + b * 512;
  int krow = tid >> 4, g = tid & 15;
  float m = -INFINITY, l = 0.f, a0 = 0.f, a1 = 0.f;
  int d0 = tid, d1 = tid + 256;
  for (int r0 = 0; r0 < 512; r0 += 16) {
    __syncthreads();
    const float* hr = hb + (size_t)(r0 + krow) * 512;
    float ep = 0.f;
    #pragma unroll
    for (int i = 0; i < 8; ++i) {
      int d = i * 64 + g * 4;
      float4 hv = *(const float4*)(hr + d);
      float4 sv = *(const float4*)(sq + d);
      ep += hv.x * sv.x + hv.y * sv.y + hv.z * sv.z + hv.w * sv.w;
      *(float4*)(&hs[krow * 512 + d]) = hv;
    }
    ep += __shfl_xor(ep, 1);
    ep += __shfl_xor(ep, 2);
    ep += __shfl_xor(ep, 4);
    ep += __shfl_xor(ep, 8);
    if (g == 0) es[krow] = ep;
    __syncthreads();
    float mc = es[0];
    #pragma unroll
    for (int k = 1; k < 16; ++k) mc = fmaxf(mc, es[k]);
    float mn = fmaxf(m, mc);
    if (tid < 16) ps[tid] = expf(es[tid] - mn);
    __syncthreads();
    float sc = expf(m - mn);
    float ls = 0.f;
    float n0 = a0 * sc, n1 = a1 * sc;
    #pragma unroll
    for (int k = 0; k < 16; ++k) {
      float p = ps[k];
      ls += p;
      n0 += p * hs[k * 512 + d0];
      n1 += p * hs[k * 512 + d1];
    }
    m = mn; l = l * sc + ls; a0 = n0; a1 = n1;
  }
  cpr[b * 512 + d0] = a0 / l;
  cpr[b * 512 + d1] = a1 / l;
}

__device__ __forceinline__ void gemm_block(
    const float* X0, const float* W0, const float* X1, const float* W1,
    float* part, float* Xs, float* Ws, int bid, int tid) {
  int jt = (bid & 15) * 128;
  int s = bid >> 4;
  const float* X; const float* W; int kbase;
  if (s < 8) { X = X0; W = W0; kbase = s * 64; }
  else       { X = X1; W = W1; kbase = (s - 8) * 64; }
  float acc[8][8];
  #pragma unroll
  for (int i = 0; i < 8; ++i)
    #pragma unroll
    for (int q = 0; q < 8; ++q) acc[i][q] = 0.f;
  int b0 = (tid & 15) * 8, j0 = (tid >> 4) * 8;
  for (int kk = 0; kk < 64; kk += 16) {
    #pragma unroll
    for (int lo = 0; lo < 2; ++lo) {
      int idx = tid + lo * 256;
      int row = idx >> 2;
      int kq = (idx & 3) * 4;
      float4 xv = *(const float4*)(X + (size_t)row * 512 + kbase + kk + kq);
      float4 wv = *(const float4*)(W + (size_t)(jt + row) * 512 + kbase + kk + kq);
      Xs[(kq + 0) * 128 + row] = xv.x; Xs[(kq + 1) * 128 + row] = xv.y;
      Xs[(kq + 2) * 128 + row] = xv.z; Xs[(kq + 3) * 128 + row] = xv.w;
      Ws[(kq + 0) * 128 + row] = wv.x; Ws[(kq + 1) * 128 + row] = wv.y;
      Ws[(kq + 2) * 128 + row] = wv.z; Ws[(kq + 3) * 128 + row] = wv.w;
    }
    __syncthreads();
    #pragma unroll
    for (int k = 0; k < 16; ++k) {
      float4 xa = *(const float4*)&Xs[k * 128 + b0];
      float4 xb = *(const float4*)&Xs[k * 128 + b0 + 4];
      float4 wa = *(const float4*)&Ws[k * 128 + j0];
      float4 wb = *(const float4*)&Ws[k * 128 + j0 + 4];
      float xr[8] = {xa.x, xa.y, xa.z, xa.w, xb.x, xb.y, xb.z, xb.w};
      float wr[8] = {wa.x, wa.y, wa.z, wa.w, wb.x, wb.y, wb.z, wb.w};
      #pragma unroll
      for (int i = 0; i < 8; ++i)
        #pragma unroll
        for (int q = 0; q < 8; ++q) acc[i][q] += xr[i] * wr[q];
    }
    __syncthreads();
  }
  #pragma unroll
  for (int i = 0; i < 8; ++i) {
    float* pr = part + ((size_t)(s * 128 + b0 + i)) * 2048 + jt + j0;
    *(float4*)pr = make_float4(acc[i][0], acc[i][1], acc[i][2], acc[i][3]);
    *(float4*)(pr + 4) = make_float4(acc[i][4], acc[i][5], acc[i][6], acc[i][7]);
  }
}

__device__ __forceinline__ void cell_block(
    const float* part, const float* biasA, const float* bi, const float* bh,
    const float* woh, int ldoh, const int* z, float* s, float* cs,
    int bid, int tid) {
  int lin = bid * 256 + tid;
  int b = lin >> 9, d = lin & 511;
  int zb = woh ? z[b] : 0;
  float g4[4];
  #pragma unroll
  for (int g = 0; g < 4; ++g) {
    int j = g * 512 + d;
    float sum = biasA ? biasA[j] : (bi[j] + bh[j]);
    if (woh) sum += woh[(size_t)j * ldoh + zb];
    #pragma unroll
    for (int sl = 0; sl < 16; ++sl)
      sum += part[((size_t)(sl * 128 + b)) * 2048 + j];
    g4[g] = sum;
  }
  float ig = sigm(g4[0]), fg = sigm(g4[1]);
  float gg = tanhf(g4[2]), og = sigm(g4[3]);
  float cn = fg * cs[lin] + ig * gg;
  float sn = og * tanhf(cn);
  cs[lin] = cn;
  s[lin] = sn;
}

__device__ __forceinline__ void outp_block(int t,
    const float* s1, const float* outw, const float* outb, const float* Amat,
    const float* vvec, const float* gum, const float* ub, const int* y,
    float* out, float* sqt, int* z, float* sl, float* red, int bid, int tid) {
  if (bid < 128) {
    int b = bid;
    for (int i = tid; i < 512; i += 256) sl[i] = s1[b * 512 + i];
    __syncthreads();
    int v = tid & 63, kg = tid >> 6;
    const float* wr = outw + (size_t)v * 512 + kg * 128;
    const float* sr = sl + kg * 128;
    float sum = 0.f;
    #pragma unroll 8
    for (int k = 0; k < 128; k += 4) {
      float4 w4 = *(const float4*)(wr + k);
      float4 s4 = *(const float4*)(sr + k);
      sum += w4.x * s4.x + w4.y * s4.y + w4.z * s4.z + w4.w * s4.w;
    }
    red[kg * 64 + v] = sum;
    __syncthreads();
    if (tid < 64) {
      float o = red[tid] + red[64 + tid] + red[128 + tid] + red[192 + tid] + outb[tid];
      out[((size_t)b * T_ + t) * VOC_ + tid] = o;
      float val = o + gum[((size_t)t * B_ + b) * VOC_ + tid];
      int idx = tid;
      #pragma unroll
      for (int off = 1; off < 64; off <<= 1) {
        float ov = __shfl_xor(val, off);
        int oi = __shfl_xor(idx, off);
        if (ov > val || (ov == val && oi < idx)) { val = ov; idx = oi; }
      }
      if (tid == 0) {
        float u = ub[t * B_ + b];
        z[b] = (u < 0.1f) ? idx : y[b * (T_ + 1) + t + 1];
      }
    }
  } else {
    int b = bid - 128;
    for (int i = tid; i < 512; i += 256) sl[i] = s1[b * 512 + i];
    __syncthreads();
    int d0 = tid, d1 = tid + 256;
    float a0v = vvec[d0], a1v = vvec[d1];
    const float* r0 = Amat + (size_t)d0 * 512;
    const float* r1 = Amat + (size_t)d1 * 512;
    for (int k = 0; k < 512; k += 4) {
      float4 s4 = *(const float4*)(sl + k);
      float4 a4 = *(const float4*)(r0 + k);
      float4 b4 = *(const float4*)(r1 + k);
      a0v += a4.x * s4.x + a4.y * s4.y + a4.z * s4.z + a4.w * s4.w;
      a1v += b4.x * s4.x + b4.y * s4.y + b4.z * s4.z + b4.w * s4.w;
    }
    sqt[b * 512 + d0] = a0v;
    sqt[b * 512 + d1] = a1v;
  }
}

// ----------------------- the persistent loop kernel --------------------
struct LoopParams {
  const float* h;
  const float* W1psi; const float* w_hh0;
  const float* w_ih1; const float* w_hh1;
  const float* bias0; const float* b_ih1; const float* b_hh1;
  const float* w_ih0;
  const float* out_w; const float* out_b;
  const float* Amat;  const float* vvec;
  const float* gum;   const float* ub;
  const int*   y;
  float* out; float* sqt; float* cpr; float* part;
  float* s0; float* cs0; float* s1; float* cs1;
  int* z;
};

// grid barrier with explicit agent-scope release/acquire fences:
// __threadfence() forces the per-XCD L2 writeback (release) before the
// rendezvous and invalidate (acquire) after, exactly what a kernel-launch
// boundary provides. cg::sync alone left deterministic stale reads (R1/R2).
__device__ __forceinline__ void gsync(cg::grid_group& g) {
  __threadfence();
  g.sync();
  __threadfence();
}

__global__ __launch_bounds__(256, 1) void k_loop(LoopParams P) {
  cg::grid_group grid = cg::this_grid();
  // attn: hs[8192]+es[16]+ps[16]; gemm: Xs[2048]+Ws[2048]; out: sl[512]+red[256]
  __shared__ __align__(16) float smem[8224];
  int bid = blockIdx.x, tid = threadIdx.x;
  for (int t = 0; t < T_; ++t) {
    if (bid < B_) attn_block(P.h, P.sqt, P.cpr, smem, smem + 8192, smem + 8208, bid, tid);
    gsync(grid);
    gemm_block(P.cpr, P.W1psi, P.s0, P.w_hh0, P.part, smem, smem + 2048, bid, tid);
    gsync(grid);
    cell_block(P.part, P.bias0, nullptr, nullptr, P.w_ih0, 576, P.z, P.s0, P.cs0, bid, tid);
    gsync(grid);
    gemm_block(P.s0, P.w_ih1, P.s1, P.w_hh1, P.part, smem, smem + 2048, bid, tid);
    gsync(grid);
    cell_block(P.part, nullptr, P.b_ih1, P.b_hh1, nullptr, 0, P.z, P.s1, P.cs1, bid, tid);
    gsync(grid);
    outp_block(t, P.s1, P.out_w, P.out_b, P.Amat, P.vvec, P.gum, P.ub, P.y,
               P.out, P.sqt, P.z, smem, smem + 512, bid, tid);
    gsync(grid);
  }
}

// =====================================================================
extern "C" void kernel_launch(void* const* d_in, const int* in_sizes, int n_in,
                              void* d_out, int out_size, void* d_ws, size_t ws_size,
                              hipStream_t stream) {
  const float* h     = (const float*)d_in[0];
  const float* phi_w = (const float*)d_in[1];
  const float* phi_b = (const float*)d_in[2];
  const float* psi_w = (const float*)d_in[3];
  const float* psi_b = (const float*)d_in[4];
  const float* w_ih0 = (const float*)d_in[5];
  const float* w_hh0 = (const float*)d_in[6];
  const float* b_ih0 = (const float*)d_in[7];
  const float* b_hh0 = (const float*)d_in[8];
  const float* w_ih1 = (const float*)d_in[9];
  const float* w_hh1 = (const float*)d_in[10];
  const float* b_ih1 = (const float*)d_in[11];
  const float* b_hh1 = (const float*)d_in[12];
  const float* out_w = (const float*)d_in[13];
  const float* out_b = (const float*)d_in[14];
  const int*   y     = (const int*)d_in[15];

  float* out = (float*)d_out;
  float* ws  = (float*)d_ws;

  float* s0    = ws + S0_OFF;
  float* cs0   = ws + CS0_OFF;
  float* s1    = ws + S1_OFF;
  float* cs1   = ws + CS1_OFF;
  float* sqt   = ws + SQT_OFF;
  float* cpr   = ws + CPR_OFF;
  float* Amat  = ws + AMAT_OFF;
  float* W1psi = ws + W1PSI_OFF;
  float* bias0 = ws + BIAS0_OFF;
  float* vvec  = ws + V_OFF;
  float* part  = ws + PART_OFF;
  float* gum   = ws + GUM_OFF;
  float* ub    = ws + UB_OFF;
  int*   z     = (int*)(ws + Z_OFF);

  // zero LSTM states (s0, cs0, s1, cs1 are contiguous)
  hipMemsetAsync(s0, 0, 4 * (size_t)B_ * HID_ * sizeof(float), stream);

  // precompute: randomness, folded matrices
  k_random<<<T_, 256, 0, stream>>>(y, gum, ub, z);
  k_fold_misc<<<10, 256, 0, stream>>>(psi_w, phi_b, w_ih0, psi_b, b_ih0, b_hh0, vvec, bias0);
  k_gemm_tn<<<dim3(16, 16), 256, 0, stream>>>(psi_w, phi_w, Amat, 512, 512, 512, 512);
  k_gemm_nn<<<dim3(16, 64), 256, 0, stream>>>(w_ih0, psi_w, W1psi, 512, 576, 64, 512, 512);
  k_sqt_init<<<256, 256, 0, stream>>>(vvec, sqt);

  // persistent cooperative loop: 1 launch, 6 fenced grid syncs per step
  LoopParams P;
  P.h = h; P.W1psi = W1psi; P.w_hh0 = w_hh0; P.w_ih1 = w_ih1; P.w_hh1 = w_hh1;
  P.bias0 = bias0; P.b_ih1 = b_ih1; P.b_hh1 = b_hh1; P.w_ih0 = w_ih0;
  P.out_w = out_w; P.out_b = out_b; P.Amat = Amat; P.vvec = vvec;
  P.gum = gum; P.ub = ub; P.y = y;
  P.out = out; P.sqt = sqt; P.cpr = cpr; P.part = part;
  P.s0 = s0; P.cs0 = cs0; P.s1 = s1; P.cs1 = cs1; P.z = z;
  void* args[] = {(void*)&P};
  hipError_t err = hipLaunchCooperativeKernel((void*)k_loop, dim3(256), dim3(256),
                                              args, 0, stream);
  if (err != hipSuccess) {
    // fallback: verbatim known-passing 6-kernel loop
    for (int t = 0; t < T_; ++t) {
      k_attn<<<128, 256, 0, stream>>>(h, sqt, cpr);
      k_lstm_gemm<<<dim3(16, 16), 256, 0, stream>>>(cpr, W1psi, s0, w_hh0, part);
      k_lstm_cell<<<256, 256, 0, stream>>>(part, bias0, nullptr, nullptr, w_ih0, 576, z, s0, cs0);
      k_lstm_gemm<<<dim3(16, 16), 256, 0, stream>>>(s0, w_ih1, s1, w_hh1, part);
      k_lstm_cell<<<256, 256, 0, stream>>>(part, nullptr, b_ih1, b_hh1, nullptr, 0, z, s1, cs1);
      k_out_sample_sqt<<<256, 256, 0, stream>>>(t, s1, out_w, out_b, Amat, vvec, gum, ub, y,
                                                out, sqt, z);
    }
  }
}

// Round 4
// 15554.254 us; speedup vs baseline: 4.9528x; 4.9528x over previous
//
#include <hip/hip_runtime.h>
#include <math.h>

// =====================================================================
// AttendAndSpell: 128-step attention LSTM decoder with exact JAX threefry
// sampling replication. All compute fp32 (no fp32 MFMA on CDNA4; bf16
// would flip gumbel-argmax decisions).
//
// R4: back to multi-kernel (persistent-coop measured DEAD: __threadfence
//     emits per-block full L2 writeback+invalidate -> ~90us/sync, 77ms).
//     Instead cut kernels/step 6 -> 4 by fusing everything after part1
//     into one b-local kernel k_tail = cell1 + logits/sample + sqt +
//     NEXT step's attention (one block per b; no cross-block deps).
//     Attention body is the register-pipelined variant proven bit-identical
//     by R1==R2 outputs. All per-element arithmetic verbatim baseline.
// =====================================================================

#define JAX_PARTITIONABLE 1

#define B_   128
#define HID_ 512
#define VOC_ 64
#define T_   128

// workspace offsets in floats (unchanged layout)
#define S0_OFF    0u
#define CS0_OFF   65536u
#define S1_OFF    131072u
#define CS1_OFF   196608u
#define SQT_OFF   262144u
#define CPR_OFF   327680u
#define AMAT_OFF  393216u     // 512x512
#define W1PSI_OFF 655360u     // 2048x512
#define BIAS0_OFF 1703936u    // 2048
#define V_OFF     1705984u    // 512
#define PART_OFF  1706496u    // 16*128*2048
#define GUM_OFF   5900800u    // 128*128*64
#define UB_OFF    6949376u    // 128*128
#define Z_OFF     6965760u    // 128 ints

#define TF_TINY 1.17549435e-38f

// ----------------------- threefry2x32 ---------------------------------
__device__ __forceinline__ void tf2x32(unsigned k0, unsigned k1,
                                       unsigned& x0, unsigned& x1) {
  unsigned ks2 = k0 ^ k1 ^ 0x1BD11BDAu;
  const unsigned ks[3] = {k0, k1, ks2};
  const int rot0[4] = {13, 15, 26, 6};
  const int rot1[4] = {17, 29, 16, 24};
  x0 += ks[0]; x1 += ks[1];
  #pragma unroll
  for (int i = 0; i < 5; ++i) {
    #pragma unroll
    for (int r = 0; r < 4; ++r) {
      int rr = (i & 1) ? rot1[r] : rot0[r];
      x0 += x1;
      x1 = (x1 << rr) | (x1 >> (32 - rr));
      x1 ^= x0;
    }
    x0 += ks[(i + 1) % 3];
    x1 += ks[(i + 2) % 3] + (unsigned)(i + 1);
  }
}

__device__ __forceinline__ float bits_to_unit(unsigned bits) {
  return __uint_as_float((bits >> 9) | 0x3f800000u) - 1.0f;
}

__global__ __launch_bounds__(256) void k_random(const int* __restrict__ y,
                                                float* __restrict__ gum,
                                                float* __restrict__ ub,
                                                int* __restrict__ z) {
  int t = blockIdx.x, tid = threadIdx.x;
  unsigned ka, kb, k1a, k1b, k2a, k2b;
#if JAX_PARTITIONABLE
  ka = 0u; kb = (unsigned)t;
  tf2x32(0u, 42u, ka, kb);
  k1a = 0u; k1b = 0u; tf2x32(ka, kb, k1a, k1b);
  k2a = 0u; k2b = 1u; tf2x32(ka, kb, k2a, k2b);
  for (int j = tid; j < B_ * VOC_; j += 256) {
    unsigned x0 = 0u, x1 = (unsigned)j;
    tf2x32(k1a, k1b, x0, x1);
    unsigned bits = x0 ^ x1;
    float f = bits_to_unit(bits);
    float u = fmaxf(TF_TINY, f * (1.0f - TF_TINY) + TF_TINY);
    gum[(size_t)t * (B_ * VOC_) + j] = -logf(-logf(u));
  }
  if (tid < B_) {
    unsigned x0 = 0u, x1 = (unsigned)tid;
    tf2x32(k2a, k2b, x0, x1);
    ub[t * B_ + tid] = bits_to_unit(x0 ^ x1);
  }
#else
  {
    unsigned x0, x1, y0, y1;
    if (t < 64) {
      x0 = 2u * t;     x1 = 128u + 2u * t;     tf2x32(0u, 42u, x0, x1); ka = x0;
      y0 = 2u * t + 1; y1 = 128u + 2u * t + 1; tf2x32(0u, 42u, y0, y1); kb = y0;
    } else {
      x0 = 2u * t - 128u; x1 = 2u * t;         tf2x32(0u, 42u, x0, x1); ka = x1;
      y0 = 2u * t - 127u; y1 = 2u * t + 1;     tf2x32(0u, 42u, y0, y1); kb = y1;
    }
    unsigned e0a = 0u, e0b = 2u; tf2x32(ka, kb, e0a, e0b);
    unsigned e1a = 1u, e1b = 3u; tf2x32(ka, kb, e1a, e1b);
    k1a = e0a; k1b = e1a; k2a = e0b; k2b = e1b;
  }
  for (int j = tid; j < B_ * VOC_; j += 256) {
    unsigned x0, x1, bits;
    if (j < 4096) { x0 = (unsigned)j; x1 = (unsigned)(4096 + j); tf2x32(k1a, k1b, x0, x1); bits = x0; }
    else          { x0 = (unsigned)(j - 4096); x1 = (unsigned)j; tf2x32(k1a, k1b, x0, x1); bits = x1; }
    float f = bits_to_unit(bits);
    float u = fmaxf(TF_TINY, f * (1.0f - TF_TINY) + TF_TINY);
    gum[(size_t)t * (B_ * VOC_) + j] = -logf(-logf(u));
  }
  if (tid < B_) {
    unsigned x0, x1, bits;
    if (tid < 64) { x0 = (unsigned)tid; x1 = (unsigned)(64 + tid); tf2x32(k2a, k2b, x0, x1); bits = x0; }
    else          { x0 = (unsigned)(tid - 64); x1 = (unsigned)tid; tf2x32(k2a, k2b, x0, x1); bits = x1; }
    ub[t * B_ + tid] = bits_to_unit(bits);
  }
#endif
  if (t == 0 && tid < B_) z[tid] = y[tid * (T_ + 1)];
}

// ----------------------- precompute folds ------------------------------
__global__ __launch_bounds__(256) void k_fold_misc(
    const float* __restrict__ psi_w, const float* __restrict__ phi_b,
    const float* __restrict__ w_ih0, const float* __restrict__ psi_b,
    const float* __restrict__ b_ih0, const float* __restrict__ b_hh0,
    float* __restrict__ vvec, float* __restrict__ bias0) {
  int gid = blockIdx.x * 256 + threadIdx.x;
  if (gid < 512) {
    float acc = 0.f;
    for (int j = 0; j < 512; ++j) acc += psi_w[j * 512 + gid] * phi_b[j];
    vvec[gid] = acc;
  } else if (gid < 512 + 2048) {
    int j = gid - 512;
    float acc = b_ih0[j] + b_hh0[j];
    const float* wr = w_ih0 + (size_t)j * 576 + 64;
    for (int d = 0; d < 512; ++d) acc += wr[d] * psi_b[d];
    bias0[j] = acc;
  }
}

__global__ __launch_bounds__(256) void k_gemm_tn(
    const float* __restrict__ A, const float* __restrict__ B, float* __restrict__ C,
    int K, int lda, int ldb, int ldc) {
  __shared__ float As[32][33], Bs[32][33];
  int n0 = blockIdx.x * 32, m0 = blockIdx.y * 32;
  int t = threadIdx.x, tx = t & 31, ty = t >> 5;
  float acc[4] = {0.f, 0.f, 0.f, 0.f};
  for (int k0 = 0; k0 < K; k0 += 32) {
    for (int l = t; l < 1024; l += 256) {
      int jj = l >> 5, mm = l & 31;
      As[jj][mm] = A[(size_t)(k0 + jj) * lda + m0 + mm];
      Bs[jj][mm] = B[(size_t)(k0 + jj) * ldb + n0 + mm];
    }
    __syncthreads();
    #pragma unroll 8
    for (int jj = 0; jj < 32; ++jj) {
      float bv = Bs[jj][tx];
      #pragma unroll
      for (int q = 0; q < 4; ++q) acc[q] += As[jj][ty + 8 * q] * bv;
    }
    __syncthreads();
  }
  #pragma unroll
  for (int q = 0; q < 4; ++q) C[(size_t)(m0 + ty + 8 * q) * ldc + n0 + tx] = acc[q];
}

__global__ __launch_bounds__(256) void k_gemm_nn(
    const float* __restrict__ A, const float* __restrict__ B, float* __restrict__ C,
    int K, int lda, int aoff, int ldb, int ldc) {
  __shared__ float As[32][33], Bs[32][33];
  int n0 = blockIdx.x * 32, m0 = blockIdx.y * 32;
  int t = threadIdx.x, tx = t & 31, ty = t >> 5;
  float acc[4] = {0.f, 0.f, 0.f, 0.f};
  for (int k0 = 0; k0 < K; k0 += 32) {
    for (int l = t; l < 1024; l += 256) {
      int r = l >> 5, c = l & 31;
      As[c][r] = A[(size_t)(m0 + r) * lda + aoff + k0 + c];
      Bs[r][c] = B[(size_t)(k0 + r) * ldb + n0 + c];
    }
    __syncthreads();
    #pragma unroll 8
    for (int kk = 0; kk < 32; ++kk) {
      float bv = Bs[kk][tx];
      #pragma unroll
      for (int q = 0; q < 4; ++q) acc[q] += As[kk][ty + 8 * q] * bv;
    }
    __syncthreads();
  }
  #pragma unroll
  for (int q = 0; q < 4; ++q) C[(size_t)(m0 + ty + 8 * q) * ldc + n0 + tx] = acc[q];
}

__global__ __launch_bounds__(256) void k_sqt_init(const float* __restrict__ vvec,
                                                  float* __restrict__ sqt) {
  int lin = blockIdx.x * 256 + threadIdx.x;
  if (lin < B_ * HID_) sqt[lin] = vvec[lin & 511];
}

// ----------------------- attention (prologue only, verbatim) -----------
__global__ __launch_bounds__(256) void k_attn(const float* __restrict__ h,
                                              const float* __restrict__ sqt,
                                              float* __restrict__ cpr) {
  __shared__ float hs[16 * 512];
  __shared__ float es[16];
  __shared__ float ps[16];
  int b = blockIdx.x, t = threadIdx.x;
  const float* hb = h + (size_t)b * 512 * 512;
  const float* sq = sqt + b * 512;
  int krow = t >> 4, g = t & 15;
  float m = -INFINITY, l = 0.f, a0 = 0.f, a1 = 0.f;
  int d0 = t, d1 = t + 256;
  for (int r0 = 0; r0 < 512; r0 += 16) {
    __syncthreads();
    const float* hr = hb + (size_t)(r0 + krow) * 512;
    float ep = 0.f;
    #pragma unroll
    for (int i = 0; i < 8; ++i) {
      int d = i * 64 + g * 4;
      float4 hv = *(const float4*)(hr + d);
      float4 sv = *(const float4*)(sq + d);
      ep += hv.x * sv.x + hv.y * sv.y + hv.z * sv.z + hv.w * sv.w;
      *(float4*)(&hs[krow * 512 + d]) = hv;
    }
    ep += __shfl_xor(ep, 1);
    ep += __shfl_xor(ep, 2);
    ep += __shfl_xor(ep, 4);
    ep += __shfl_xor(ep, 8);
    if (g == 0) es[krow] = ep;
    __syncthreads();
    float mc = es[0];
    #pragma unroll
    for (int k = 1; k < 16; ++k) mc = fmaxf(mc, es[k]);
    float mn = fmaxf(m, mc);
    if (t < 16) ps[t] = expf(es[t] - mn);
    __syncthreads();
    float sc = expf(m - mn);
    float ls = 0.f;
    float n0 = a0 * sc, n1 = a1 * sc;
    #pragma unroll
    for (int k = 0; k < 16; ++k) {
      float p = ps[k];
      ls += p;
      n0 += p * hs[k * 512 + d0];
      n1 += p * hs[k * 512 + d1];
    }
    m = mn; l = l * sc + ls; a0 = n0; a1 = n1;
  }
  cpr[b * 512 + d0] = a0 / l;
  cpr[b * 512 + d1] = a1 / l;
}

// ----------------------- LSTM gate GEMM (split-K=16) -------------------
__global__ __launch_bounds__(256) void k_lstm_gemm(
    const float* __restrict__ X0, const float* __restrict__ W0,
    const float* __restrict__ X1, const float* __restrict__ W1,
    float* __restrict__ part) {
  __shared__ float Xs[16][128];
  __shared__ float Ws[16][128];
  int t = threadIdx.x;
  int jt = blockIdx.x * 128;
  int s = blockIdx.y;
  const float* X; const float* W; int kbase;
  if (s < 8) { X = X0; W = W0; kbase = s * 64; }
  else       { X = X1; W = W1; kbase = (s - 8) * 64; }
  float acc[8][8];
  #pragma unroll
  for (int i = 0; i < 8; ++i)
    #pragma unroll
    for (int q = 0; q < 8; ++q) acc[i][q] = 0.f;
  int b0 = (t & 15) * 8, j0 = (t >> 4) * 8;
  for (int kk = 0; kk < 64; kk += 16) {
    #pragma unroll
    for (int lo = 0; lo < 2; ++lo) {
      int idx = t + lo * 256;
      int row = idx >> 2;
      int kq = (idx & 3) * 4;
      float4 xv = *(const float4*)(X + (size_t)row * 512 + kbase + kk + kq);
      float4 wv = *(const float4*)(W + (size_t)(jt + row) * 512 + kbase + kk + kq);
      Xs[kq + 0][row] = xv.x; Xs[kq + 1][row] = xv.y;
      Xs[kq + 2][row] = xv.z; Xs[kq + 3][row] = xv.w;
      Ws[kq + 0][row] = wv.x; Ws[kq + 1][row] = wv.y;
      Ws[kq + 2][row] = wv.z; Ws[kq + 3][row] = wv.w;
    }
    __syncthreads();
    #pragma unroll
    for (int k = 0; k < 16; ++k) {
      float4 xa = *(const float4*)&Xs[k][b0];
      float4 xb = *(const float4*)&Xs[k][b0 + 4];
      float4 wa = *(const float4*)&Ws[k][j0];
      float4 wb = *(const float4*)&Ws[k][j0 + 4];
      float xr[8] = {xa.x, xa.y, xa.z, xa.w, xb.x, xb.y, xb.z, xb.w};
      float wr[8] = {wa.x, wa.y, wa.z, wa.w, wb.x, wb.y, wb.z, wb.w};
      #pragma unroll
      for (int i = 0; i < 8; ++i)
        #pragma unroll
        for (int q = 0; q < 8; ++q) acc[i][q] += xr[i] * wr[q];
    }
    __syncthreads();
  }
  #pragma unroll
  for (int i = 0; i < 8; ++i) {
    float* pr = part + ((size_t)(s * 128 + b0 + i)) * 2048 + jt + j0;
    *(float4*)pr = make_float4(acc[i][0], acc[i][1], acc[i][2], acc[i][3]);
    *(float4*)(pr + 4) = make_float4(acc[i][4], acc[i][5], acc[i][6], acc[i][7]);
  }
}

// ----------------------- LSTM cell finalize (cell0) --------------------
__device__ __forceinline__ float sigm(float x) { return 1.0f / (1.0f + expf(-x)); }

__global__ __launch_bounds__(256) void k_lstm_cell(
    const float* __restrict__ part, const float* __restrict__ biasA,
    const float* __restrict__ bi, const float* __restrict__ bh,
    const float* __restrict__ woh, int ldoh,
    const int* __restrict__ z, float* __restrict__ s, float* __restrict__ cs) {
  int lin = blockIdx.x * 256 + threadIdx.x;  // 0..65535
  int b = lin >> 9, d = lin & 511;
  int zb = woh ? z[b] : 0;
  float g4[4];
  #pragma unroll
  for (int g = 0; g < 4; ++g) {
    int j = g * 512 + d;
    float sum = biasA ? biasA[j] : (bi[j] + bh[j]);
    if (woh) sum += woh[(size_t)j * ldoh + zb];
    #pragma unroll
    for (int sl = 0; sl < 16; ++sl)
      sum += part[((size_t)(sl * 128 + b)) * 2048 + j];
    g4[g] = sum;
  }
  float ig = sigm(g4[0]), fg = sigm(g4[1]);
  float gg = tanhf(g4[2]), og = sigm(g4[3]);
  float cn = fg * cs[lin] + ig * gg;
  float sn = og * tanhf(cn);
  cs[lin] = cn;
  s[lin] = sn;
}

// ====== fused tail: cell1 + logits/sample + sqt + NEXT-step attention ==
// One block per batch element b. Everything after part1 is b-local:
//   cell1 (in-place cs1, own elements), logits+gumbel sample, sqt into
//   LDS, then pipelined attention for step t+1 writing cpr.
// Per-element arithmetic is verbatim baseline; attention body is the
// register-pipelined variant (R1==R2 proved it bit-identical).
__global__ __launch_bounds__(256) void k_tail(
    int t, const float* __restrict__ part,
    const float* __restrict__ bi, const float* __restrict__ bh,
    const float* __restrict__ outw, const float* __restrict__ outb,
    const float* __restrict__ Amat, const float* __restrict__ vvec,
    const float* __restrict__ gum, const float* __restrict__ ub,
    const int* __restrict__ y, const float* __restrict__ h,
    float* __restrict__ out, float* __restrict__ s1g, float* __restrict__ cs1,
    int* __restrict__ z, float* __restrict__ cpr) {
  __shared__ __align__(16) float hs[16 * 512];
  __shared__ __align__(16) float sl[512];
  __shared__ __align__(16) float sq[512];
  __shared__ float red[256];
  __shared__ float es[16];
  int b = blockIdx.x, tid = threadIdx.x;

  // ---- cell1 for this b (same per-element expr/order as k_lstm_cell) --
  #pragma unroll
  for (int half = 0; half < 2; ++half) {
    int d = tid + half * 256;
    int lin = b * 512 + d;
    float g4[4];
    #pragma unroll
    for (int g = 0; g < 4; ++g) {
      int j = g * 512 + d;
      float sum = bi[j] + bh[j];
      #pragma unroll
      for (int slc = 0; slc < 16; ++slc)
        sum += part[((size_t)(slc * 128 + b)) * 2048 + j];
      g4[g] = sum;
    }
    float ig = sigm(g4[0]), fg = sigm(g4[1]);
    float gg = tanhf(g4[2]), og = sigm(g4[3]);
    float cn = fg * cs1[lin] + ig * gg;
    float sn = og * tanhf(cn);
    cs1[lin] = cn;
    s1g[lin] = sn;   // next step's gemm1 X1 operand
    sl[d] = sn;
  }
  __syncthreads();

  // ---- logits + gumbel-argmax sample (verbatim baseline path) ---------
  {
    int v = tid & 63, kg = tid >> 6;
    const float* wr = outw + (size_t)v * 512 + kg * 128;
    const float* sr = sl + kg * 128;
    float sum = 0.f;
    #pragma unroll 8
    for (int k = 0; k < 128; k += 4) {
      float4 w4 = *(const float4*)(wr + k);
      float4 s4 = *(const float4*)(sr + k);
      sum += w4.x * s4.x + w4.y * s4.y + w4.z * s4.z + w4.w * s4.w;
    }
    red[kg * 64 + v] = sum;
    __syncthreads();
    if (tid < 64) {
      float o = red[tid] + red[64 + tid] + red[128 + tid] + red[192 + tid] + outb[tid];
      out[((size_t)b * T_ + t) * VOC_ + tid] = o;
      float val = o + gum[((size_t)t * B_ + b) * VOC_ + tid];
      int idx = tid;
      #pragma unroll
      for (int off = 1; off < 64; off <<= 1) {
        float ov = __shfl_xor(val, off);
        int oi = __shfl_xor(idx, off);
        if (ov > val || (ov == val && oi < idx)) { val = ov; idx = oi; }
      }
      if (tid == 0) {
        float u = ub[t * B_ + b];
        z[b] = (u < 0.1f) ? idx : y[b * (T_ + 1) + t + 1];
      }
    }
  }

  // ---- sqt for step t+1 (verbatim baseline path, into LDS) ------------
  {
    int d0 = tid, d1 = tid + 256;
    float a0v = vvec[d0], a1v = vvec[d1];
    const float* r0 = Amat + (size_t)d0 * 512;
    const float* r1 = Amat + (size_t)d1 * 512;
    for (int k = 0; k < 512; k += 4) {
      float4 s4 = *(const float4*)(sl + k);
      float4 a4 = *(const float4*)(r0 + k);
      float4 b4 = *(const float4*)(r1 + k);
      a0v += a4.x * s4.x + a4.y * s4.y + a4.z * s4.z + a4.w * s4.w;
      a1v += b4.x * s4.x + b4.y * s4.y + b4.z * s4.z + b4.w * s4.w;
    }
    sq[d0] = a0v;
    sq[d1] = a1v;
  }
  if (t == T_ - 1) return;   // no consumer for attn(t+1) after last step
  __syncthreads();

  // ---- pipelined attention for step t+1 (bit-identical order) ---------
  const float* hb = h + (size_t)b * (512 * 512);
  int krow = tid >> 4, gq = tid & 15;
  int col = gq * 4;
  float4 sqr[8];
  #pragma unroll
  for (int i = 0; i < 8; ++i) sqr[i] = *(const float4*)(&sq[i * 64 + col]);
  float4 hv[8];
  // prologue: chunk 0 -> hs, es
  {
    const float* hr = hb + (size_t)krow * 512;
    #pragma unroll
    for (int i = 0; i < 8; ++i) hv[i] = *(const float4*)(hr + i * 64 + col);
    float ep = 0.f;
    #pragma unroll
    for (int i = 0; i < 8; ++i) {
      ep += hv[i].x * sqr[i].x + hv[i].y * sqr[i].y + hv[i].z * sqr[i].z + hv[i].w * sqr[i].w;
      *(float4*)(&hs[krow * 512 + i * 64 + col]) = hv[i];
    }
    ep += __shfl_xor(ep, 1); ep += __shfl_xor(ep, 2);
    ep += __shfl_xor(ep, 4); ep += __shfl_xor(ep, 8);
    if (gq == 0) es[krow] = ep;
  }
  __syncthreads();
  float m = -INFINITY, l = 0.f, a0 = 0.f, a1 = 0.f;
  int d0 = tid, d1 = tid + 256;
  int lane15 = tid & 15;
  for (int c = 0; c < 32; ++c) {
    // 1. prefetch chunk c+1 into registers (consumed in step 3)
    if (c < 31) {
      const float* hr = hb + (size_t)((c + 1) * 16 + krow) * 512;
      #pragma unroll
      for (int i = 0; i < 8; ++i) hv[i] = *(const float4*)(hr + i * 64 + col);
    }
    // 2. softmax-accumulate chunk c (p values bitwise == baseline ps[k])
    float mc = es[0];
    #pragma unroll
    for (int k = 1; k < 16; ++k) mc = fmaxf(mc, es[k]);
    float mn = fmaxf(m, mc);
    float pw = expf(es[lane15] - mn);
    float sc = expf(m - mn);
    float ls = 0.f;
    float n0 = a0 * sc, n1 = a1 * sc;
    #pragma unroll
    for (int k = 0; k < 16; ++k) {
      float p = __shfl(pw, k);
      ls += p;
      n0 += p * hs[k * 512 + d0];
      n1 += p * hs[k * 512 + d1];
    }
    m = mn; l = l * sc + ls; a0 = n0; a1 = n1;
    __syncthreads();
    // 3. write chunk c+1 into hs, compute its es
    if (c < 31) {
      float ep = 0.f;
      #pragma unroll
      for (int i = 0; i < 8; ++i) {
        ep += hv[i].x * sqr[i].x + hv[i].y * sqr[i].y + hv[i].z * sqr[i].z + hv[i].w * sqr[i].w;
        *(float4*)(&hs[krow * 512 + i * 64 + col]) = hv[i];
      }
      ep += __shfl_xor(ep, 1); ep += __shfl_xor(ep, 2);
      ep += __shfl_xor(ep, 4); ep += __shfl_xor(ep, 8);
      if (gq == 0) es[krow] = ep;
    }
    __syncthreads();
  }
  cpr[b * 512 + d0] = a0 / l;
  cpr[b * 512 + d1] = a1 / l;
}

// =====================================================================
extern "C" void kernel_launch(void* const* d_in, const int* in_sizes, int n_in,
                              void* d_out, int out_size, void* d_ws, size_t ws_size,
                              hipStream_t stream) {
  const float* h     = (const float*)d_in[0];
  const float* phi_w = (const float*)d_in[1];
  const float* phi_b = (const float*)d_in[2];
  const float* psi_w = (const float*)d_in[3];
  const float* psi_b = (const float*)d_in[4];
  const float* w_ih0 = (const float*)d_in[5];
  const float* w_hh0 = (const float*)d_in[6];
  const float* b_ih0 = (const float*)d_in[7];
  const float* b_hh0 = (const float*)d_in[8];
  const float* w_ih1 = (const float*)d_in[9];
  const float* w_hh1 = (const float*)d_in[10];
  const float* b_ih1 = (const float*)d_in[11];
  const float* b_hh1 = (const float*)d_in[12];
  const float* out_w = (const float*)d_in[13];
  const float* out_b = (const float*)d_in[14];
  const int*   y     = (const int*)d_in[15];

  float* out = (float*)d_out;
  float* ws  = (float*)d_ws;

  float* s0    = ws + S0_OFF;
  float* cs0   = ws + CS0_OFF;
  float* s1    = ws + S1_OFF;
  float* cs1   = ws + CS1_OFF;
  float* sqt   = ws + SQT_OFF;
  float* cpr   = ws + CPR_OFF;
  float* Amat  = ws + AMAT_OFF;
  float* W1psi = ws + W1PSI_OFF;
  float* bias0 = ws + BIAS0_OFF;
  float* vvec  = ws + V_OFF;
  float* part  = ws + PART_OFF;
  float* gum   = ws + GUM_OFF;
  float* ub    = ws + UB_OFF;
  int*   z     = (int*)(ws + Z_OFF);

  // zero LSTM states (s0, cs0, s1, cs1 are contiguous)
  hipMemsetAsync(s0, 0, 4 * (size_t)B_ * HID_ * sizeof(float), stream);

  // precompute: randomness, folded matrices
  k_random<<<T_, 256, 0, stream>>>(y, gum, ub, z);
  k_fold_misc<<<10, 256, 0, stream>>>(psi_w, phi_b, w_ih0, psi_b, b_ih0, b_hh0, vvec, bias0);
  // Amat = psi_w^T @ phi_w (512x512)
  k_gemm_tn<<<dim3(16, 16), 256, 0, stream>>>(psi_w, phi_w, Amat, 512, 512, 512, 512);
  // W1psi = w_ih0[:,64:576] @ psi_w (2048x512)
  k_gemm_nn<<<dim3(16, 64), 256, 0, stream>>>(w_ih0, psi_w, W1psi, 512, 576, 64, 512, 512);
  // sqt for step 0: s1 = 0 -> sqt = v broadcast; then attention once
  k_sqt_init<<<256, 256, 0, stream>>>(vvec, sqt);
  k_attn<<<128, 256, 0, stream>>>(h, sqt, cpr);

  // main loop: 4 kernels per step
  for (int t = 0; t < T_; ++t) {
    k_lstm_gemm<<<dim3(16, 16), 256, 0, stream>>>(cpr, W1psi, s0, w_hh0, part);
    k_lstm_cell<<<256, 256, 0, stream>>>(part, bias0, nullptr, nullptr, w_ih0, 576, z, s0, cs0);
    k_lstm_gemm<<<dim3(16, 16), 256, 0, stream>>>(s0, w_ih1, s1, w_hh1, part);
    k_tail<<<128, 256, 0, stream>>>(t, part, b_ih1, b_hh1, out_w, out_b, Amat, vvec,
                                    gum, ub, y, h, out, s1, cs1, z, cpr);
  }
}